// Round 3
// baseline (93602.594 us; speedup 1.0000x reference)
//
#include <hip/hip_runtime.h>

#define DEV __device__ __forceinline__

typedef __attribute__((ext_vector_type(8))) short short8;
typedef __attribute__((ext_vector_type(4))) float floatx4;
typedef __attribute__((ext_vector_type(4))) unsigned int u32x4;
typedef unsigned short u16;
typedef unsigned int u32;

namespace {

constexpr int B_ = 32;
constexpr int S_ = 2048;
constexpr int IN0 = 256;
constexpr int H_ = 512;
constexpr size_t Y1_ELEMS = (size_t)B_ * S_ * H_;

// ---- workspace layout (bytes). ws is poisoned 0xAA each launch; flags are
// ints, poison = 0xAAAAAAAA < 0 < any target (t+1 >= 1), so no init needed.
constexpr size_t O_Y0HI = 0;                                  // u16 [8][32][512] ring
constexpr size_t O_Y0LO = O_Y0HI + (size_t)8 * B_ * H_ * 2;
constexpr size_t O_Y1HI = O_Y0LO + (size_t)8 * B_ * H_ * 2;   // u16 [4][32][512] ring
constexpr size_t O_Y1LO = O_Y1HI + (size_t)4 * B_ * H_ * 2;
constexpr size_t O_RHHI = O_Y1LO + (size_t)4 * B_ * H_ * 2;   // u16 [2][32][512]
constexpr size_t O_RHLO = O_RHHI + (size_t)2 * B_ * H_ * 2;
constexpr size_t O_ZBUF = O_RHLO + (size_t)2 * B_ * H_ * 2;   // f32 [2][32][512]
constexpr size_t O_FLAG = O_ZBUF + (size_t)2 * B_ * H_ * 4;   // fA[2][32][2], fH[2][32][2], abort
constexpr size_t WS_NEED = O_FLAG + 4096;

struct GruArgs {
  const float* x;  const float* h0;
  const float* Wz0; const float* bz0; const float* Wr0; const float* br0;
  const float* Wh0; const float* bh0;
  const float* Wz1; const float* bz1; const float* Wr1; const float* br1;
  const float* Wh1; const float* bh1;
  float* out; char* ws;
};

DEV u16 f2bf(float f) {  // RNE fp32 -> bf16 bits
  u32 u = __builtin_bit_cast(u32, f);
  return (u16)((u + 0x7fffu + ((u >> 16) & 1u)) >> 16);
}
DEV float bf2f(u16 h) { u32 u = ((u32)h) << 16; return __builtin_bit_cast(float, u); }

// Agent-scope coherent (coherence-point) u32 load — immune to stale L1/L2.
DEV u32 ald(const u32* p) {
  return __hip_atomic_load(p, __ATOMIC_RELAXED, __HIP_MEMORY_SCOPE_AGENT);
}

// A/B fragment for mfma_f32_16x16x32_bf16:
//   A: row = lane&15, k = 8*(lane>>4)+e ; B: col = lane&15, k = 8*(lane>>4)+e
//   D: col = lane&15, row = 4*(lane>>4)+reg   (guide-verified C/D layout, m89)
DEV short8 frag_lds(const u16* base, int ld, int k0) {  // LDS weights (plain)
  const int l = threadIdx.x & 63;
  return *reinterpret_cast<const short8*>(base + (size_t)(l & 15) * ld + k0 + ((l >> 4) << 3));
}
DEV short8 frag_coh(const u16* base, int ld, int k0) {  // cross-block ring planes
  const int l = threadIdx.x & 63;
  const u32* p = reinterpret_cast<const u32*>(base + (size_t)(l & 15) * ld + k0 + ((l >> 4) << 3));
  u32x4 w;
  w[0] = ald(p + 0); w[1] = ald(p + 1); w[2] = ald(p + 2); w[3] = ald(p + 3);
  return __builtin_bit_cast(short8, w);
}
// Coherent scalar read of hi/lo bf16 plane pair -> fp32
DEV float pair_coh(const u16* hi, const u16* lo, size_t idx) {
  const size_t e = idx & ~(size_t)1;
  u32 wh = ald(reinterpret_cast<const u32*>(hi + e));
  u32 wl = ald(reinterpret_cast<const u32*>(lo + e));
  const int sh = (int)(idx & 1) * 16;
  return bf2f((u16)(wh >> sh)) + bf2f((u16)(wl >> sh));
}
DEV void frag_f32(const float* base, size_t ld, int k0, short8& hi, short8& lo) {
  const int l = threadIdx.x & 63;
  const float* p = base + (size_t)(l & 15) * ld + k0 + ((l >> 4) << 3);
  float4 a = *reinterpret_cast<const float4*>(p);
  float4 b = *reinterpret_cast<const float4*>(p + 4);
  float v[8] = {a.x, a.y, a.z, a.w, b.x, b.y, b.z, b.w};
#pragma unroll
  for (int e = 0; e < 8; ++e) {
    u16 h = f2bf(v[e]);
    hi[e] = (short)h;
    lo[e] = (short)f2bf(v[e] - bf2f(h));
  }
}

// 3-term hi/lo split product accumulate (drops lo*lo, ~2^-17 rel)
DEV floatx4 acc3(floatx4 c, short8 ahi, short8 alo, const u16* whi, const u16* wlo,
                 int ld, int k0) {
  short8 bh = frag_lds(whi, ld, k0);
  short8 bl = frag_lds(wlo, ld, k0);
  c = __builtin_amdgcn_mfma_f32_16x16x32_bf16(ahi, bh, c, 0, 0, 0);
  c = __builtin_amdgcn_mfma_f32_16x16x32_bf16(alo, bh, c, 0, 0, 0);
  c = __builtin_amdgcn_mfma_f32_16x16x32_bf16(ahi, bl, c, 0, 0, 0);
  return c;
}

// Wave 0 polls cnt flags (lane i -> base[i*stride]); all waves barrier, then
// acquire-fence (agent). Watchdog sets global abort magic instead of hanging.
DEV void wait_all(int* base, int cnt, int stride, int target, int* abortf) {
  if ((threadIdx.x >> 6) == 0) {
    const int l = threadIdx.x & 63;
    if (l < cnt) {
      int* p = base + l * stride;
      int it = 0;
      while (__hip_atomic_load(p, __ATOMIC_RELAXED, __HIP_MEMORY_SCOPE_AGENT) < target) {
        __builtin_amdgcn_s_sleep(1);
        if ((++it & 1023) == 0) {
          if (__hip_atomic_load(abortf, __ATOMIC_RELAXED, __HIP_MEMORY_SCOPE_AGENT) == 1234567) break;
          if (it > (1 << 22)) {
            __hip_atomic_store(abortf, 1234567, __ATOMIC_RELAXED, __HIP_MEMORY_SCOPE_AGENT);
            break;
          }
        }
      }
    }
  }
  __syncthreads();
  __builtin_amdgcn_fence(__ATOMIC_ACQUIRE, "agent");
}

// Per-thread release ordering + barrier, then one RELEASE flag store by tid 0.
DEV void publish_flag(int* flag, int value) {
  __builtin_amdgcn_fence(__ATOMIC_RELEASE, "agent");
  __syncthreads();
  if (threadIdx.x == 0)
    __hip_atomic_store(flag, value, __ATOMIC_RELEASE, __HIP_MEMORY_SCOPE_AGENT);
}

DEV void store_pair_u16(u16* plane, size_t idx_even, u16 el_lo, u16 el_hi) {
  u32 v = (u32)el_lo | ((u32)el_hi << 16);
  __hip_atomic_store(reinterpret_cast<u32*>(plane + idx_even), v,
                     __ATOMIC_RELAXED, __HIP_MEMORY_SCOPE_AGENT);
}

// ---------------- Role A: z,r gates + publish r*h (hi/lo planes) + z --------
template <int L>
DEV void role_A(const GruArgs& a, int colb, int bg, u16* sWT, float* sRedF, float* sBias) {
  constexpr int KX = (L == 0) ? IN0 : H_;   // input-part K
  constexpr int KPAD = KX + H_ + 8;         // LDS row stride (u16), keeps 16B align
  constexpr int KXq = KX / 4;               // per-wave input-part slice
  const int tid = threadIdx.x;
  const int w = tid >> 6;
  const int l = tid & 63;
  const int j0 = colb * 16, b0 = bg * 16;

  const float* Wz = L ? a.Wz1 : a.Wz0;
  const float* Wr = L ? a.Wr1 : a.Wr0;
  const float* bz = L ? a.bz1 : a.bz0;
  const float* br = L ? a.br1 : a.br0;

  // pack weight slice hi/lo into LDS, layout [gate][plane][16 cols][KPAD]
  for (int g = 0; g < 2; ++g) {
    const float* W = g ? Wr : Wz;
    const int c = tid & 15;
    for (int k = tid >> 4; k < KX + H_; k += 16) {
      float v = W[(size_t)k * H_ + j0 + c];
      u16 h = f2bf(v), lo = f2bf(v - bf2f(h));
      sWT[((size_t)(g * 2 + 0) * 16 + c) * KPAD + k] = h;
      sWT[((size_t)(g * 2 + 1) * 16 + c) * KPAD + k] = lo;
    }
  }
  if (tid < 16) { sBias[0 * 16 + tid] = bz[j0 + tid]; sBias[1 * 16 + tid] = br[j0 + tid]; }
  __syncthreads();

  char* ws = a.ws;
  u16* y0hi = (u16*)(ws + O_Y0HI); u16* y0lo = (u16*)(ws + O_Y0LO);
  u16* y1hi = (u16*)(ws + O_Y1HI); u16* y1lo = (u16*)(ws + O_Y1LO);
  u16* rhhi = (u16*)(ws + O_RHHI) + (size_t)L * B_ * H_;
  u16* rhlo = (u16*)(ws + O_RHLO) + (size_t)L * B_ * H_;
  float* zb = (float*)(ws + O_ZBUF) + (size_t)L * B_ * H_;
  int* fA = (int*)(ws + O_FLAG);
  int* fH = fA + 128;
  int* abortf = fH + 128;
  int* fA_mine = fA + (L * 64 + colb * 2 + bg);
  int* fH_L0 = fH;
  int* fH_self = fH + L * 64;
  const float* h0p = a.h0 + (size_t)L * B_ * H_;

  const u16* wz_hi = sWT + (size_t)0 * 16 * KPAD;
  const u16* wz_lo = sWT + (size_t)1 * 16 * KPAD;
  const u16* wr_hi = sWT + (size_t)2 * 16 * KPAD;
  const u16* wr_lo = sWT + (size_t)3 * 16 * KPAD;

  for (int t = 0; t < S_; ++t) {
    floatx4 az = {0.f, 0.f, 0.f, 0.f};
    floatx4 ar = {0.f, 0.f, 0.f, 0.f};

    // ---- input-part of z,r  (x for L0: no wait; y0(t) for L1)
    if constexpr (L == 0) {
      const float* xb = a.x + ((size_t)b0 * S_ + t) * IN0;
#pragma unroll
      for (int k = 0; k < KXq; k += 32) {
        short8 hi, lo;
        frag_f32(xb, (size_t)S_ * IN0, w * KXq + k, hi, lo);
        az = acc3(az, hi, lo, wz_hi, wz_lo, KPAD, w * KXq + k);
        ar = acc3(ar, hi, lo, wr_hi, wr_lo, KPAD, w * KXq + k);
      }
    } else {
      wait_all(fH_L0 + bg, 32, 2, t + 1, abortf);
      const u16* ph = y0hi + ((size_t)(t & 7) * B_ + b0) * H_;
      const u16* pl = y0lo + ((size_t)(t & 7) * B_ + b0) * H_;
#pragma unroll
      for (int k = 0; k < KXq; k += 32) {
        short8 hi = frag_coh(ph, H_, w * KXq + k);
        short8 lo = frag_coh(pl, H_, w * KXq + k);
        az = acc3(az, hi, lo, wz_hi, wz_lo, KPAD, w * KXq + k);
        ar = acc3(ar, hi, lo, wr_hi, wr_lo, KPAD, w * KXq + k);
      }
    }

    // ---- hidden-part of z,r
    const u16* hhi_t = nullptr; const u16* hlo_t = nullptr;  // row-0 base of h(t) planes
    if (t > 0) {
      wait_all(fH_self + bg, 32, 2, t, abortf);
      const int slot = L ? ((t - 1) & 3) : ((t - 1) & 7);
      hhi_t = (L ? y1hi : y0hi) + (size_t)slot * B_ * H_;
      hlo_t = (L ? y1lo : y0lo) + (size_t)slot * B_ * H_;
      const u16* ph = hhi_t + (size_t)b0 * H_;
      const u16* pl = hlo_t + (size_t)b0 * H_;
#pragma unroll
      for (int k = 0; k < 128; k += 32) {
        short8 hi = frag_coh(ph, H_, w * 128 + k);
        short8 lo = frag_coh(pl, H_, w * 128 + k);
        az = acc3(az, hi, lo, wz_hi, wz_lo, KPAD, KX + w * 128 + k);
        ar = acc3(ar, hi, lo, wr_hi, wr_lo, KPAD, KX + w * 128 + k);
      }
    } else {
      const float* hb = h0p + (size_t)b0 * H_;
#pragma unroll
      for (int k = 0; k < 128; k += 32) {
        short8 hi, lo;
        frag_f32(hb, (size_t)H_, w * 128 + k, hi, lo);
        az = acc3(az, hi, lo, wz_hi, wz_lo, KPAD, KX + w * 128 + k);
        ar = acc3(ar, hi, lo, wr_hi, wr_lo, KPAD, KX + w * 128 + k);
      }
    }

    // ---- cross-wave K reduce: sRed[gate][wave][col][row]
    *reinterpret_cast<floatx4*>(&sRedF[((0 * 4 + w) * 16 + (l & 15)) * 16 + ((l >> 4) << 2)]) = az;
    *reinterpret_cast<floatx4*>(&sRedF[((1 * 4 + w) * 16 + (l & 15)) * 16 + ((l >> 4) << 2)]) = ar;
    __syncthreads();
    {
      const int j = tid >> 4, brow = tid & 15, b = b0 + brow;
      float vz = sBias[0 * 16 + j], vr = sBias[1 * 16 + j];
#pragma unroll
      for (int ww = 0; ww < 4; ++ww) {
        vz += sRedF[((0 * 4 + ww) * 16 + j) * 16 + brow];
        vr += sRedF[((1 * 4 + ww) * 16 + j) * 16 + brow];
      }
      float z = 1.f / (1.f + expf(-vz));
      float r = 1.f / (1.f + expf(-vr));
      float hv = (t == 0) ? h0p[(size_t)b * H_ + j0 + j]
                          : pair_coh(hhi_t, hlo_t, (size_t)b * H_ + j0 + j);
      float rh = r * hv;
      u16 rh_h = f2bf(rh), rh_l = f2bf(rh - bf2f(rh_h));
      int prt_h = __shfl_xor((int)rh_h, 16);
      int prt_l = __shfl_xor((int)rh_l, 16);
      if ((j & 1) == 0) {
        size_t idx = (size_t)b * H_ + j0 + j;
        store_pair_u16(rhhi, idx, rh_h, (u16)prt_h);
        store_pair_u16(rhlo, idx, rh_l, (u16)prt_l);
      }
      __hip_atomic_store(zb + (size_t)b * H_ + j0 + j, z, __ATOMIC_RELAXED, __HIP_MEMORY_SCOPE_AGENT);
    }
    publish_flag(fA_mine, t + 1);
  }
}

// ---------------- Role B: h_tilde + state update + publish h planes --------
template <int L>
DEV void role_B(const GruArgs& a, int colb, int bg, u16* sWT, float* sRedF, float* sBias) {
  constexpr int KX = (L == 0) ? IN0 : H_;
  constexpr int KPADB = H_ + 8;  // 520, shared stride for both gates
  constexpr int KXq = KX / 4;
  const int tid = threadIdx.x;
  const int w = tid >> 6;
  const int l = tid & 63;
  const int j0 = colb * 16, b0 = bg * 16;

  const float* Wh = L ? a.Wh1 : a.Wh0;
  const float* bh = L ? a.bh1 : a.bh0;

  // gate0 = x-part rows [0,KX), gate1 = h-part rows [KX,KX+512)
  {
    const int c = tid & 15;
    for (int k = tid >> 4; k < KX; k += 16) {
      float v = Wh[(size_t)k * H_ + j0 + c];
      u16 h = f2bf(v), lo = f2bf(v - bf2f(h));
      sWT[((size_t)0 * 16 + c) * KPADB + k] = h;
      sWT[((size_t)1 * 16 + c) * KPADB + k] = lo;
    }
    for (int k = tid >> 4; k < H_; k += 16) {
      float v = Wh[(size_t)(KX + k) * H_ + j0 + c];
      u16 h = f2bf(v), lo = f2bf(v - bf2f(h));
      sWT[((size_t)2 * 16 + c) * KPADB + k] = h;
      sWT[((size_t)3 * 16 + c) * KPADB + k] = lo;
    }
  }
  if (tid < 16) sBias[tid] = bh[j0 + tid];
  __syncthreads();

  char* ws = a.ws;
  u16* y0hi = (u16*)(ws + O_Y0HI); u16* y0lo = (u16*)(ws + O_Y0LO);
  u16* y1hi = (u16*)(ws + O_Y1HI); u16* y1lo = (u16*)(ws + O_Y1LO);
  u16* rhhi = (u16*)(ws + O_RHHI) + (size_t)L * B_ * H_;
  u16* rhlo = (u16*)(ws + O_RHLO) + (size_t)L * B_ * H_;
  float* zb = (float*)(ws + O_ZBUF) + (size_t)L * B_ * H_;
  int* fA = (int*)(ws + O_FLAG);
  int* fH = fA + 128;
  int* abortf = fH + 128;
  int* fA_bg = fA + L * 64 + bg;  // all 32 colb producers of rh for this bg
  int* fH_L0 = fH;
  int* fH_L1 = fH + 64;
  int* fH_self = fH + L * 64;
  const float* h0p = a.h0 + (size_t)L * B_ * H_;

  const u16* wx_hi = sWT + (size_t)0 * 16 * KPADB;
  const u16* wx_lo = sWT + (size_t)1 * 16 * KPADB;
  const u16* wh_hi = sWT + (size_t)2 * 16 * KPADB;
  const u16* wh_lo = sWT + (size_t)3 * 16 * KPADB;

  for (int t = 0; t < S_; ++t) {
    floatx4 ah = {0.f, 0.f, 0.f, 0.f};

    // ---- x-part of h_tilde preact
    if constexpr (L == 0) {
      const float* xb = a.x + ((size_t)b0 * S_ + t) * IN0;
#pragma unroll
      for (int k = 0; k < KXq; k += 32) {
        short8 hi, lo;
        frag_f32(xb, (size_t)S_ * IN0, w * KXq + k, hi, lo);
        ah = acc3(ah, hi, lo, wx_hi, wx_lo, KPADB, w * KXq + k);
      }
    } else {
      wait_all(fH_L0 + bg, 32, 2, t + 1, abortf);
      const u16* ph = y0hi + ((size_t)(t & 7) * B_ + b0) * H_;
      const u16* pl = y0lo + ((size_t)(t & 7) * B_ + b0) * H_;
#pragma unroll
      for (int k = 0; k < KXq; k += 32) {
        short8 hi = frag_coh(ph, H_, w * KXq + k);
        short8 lo = frag_coh(pl, H_, w * KXq + k);
        ah = acc3(ah, hi, lo, wx_hi, wx_lo, KPADB, w * KXq + k);
      }
    }

    // ---- (r*h) @ Whh : consumes rh from ALL 32 colb producers of this bg
    wait_all(fA_bg, 32, 2, t + 1, abortf);
    {
      const u16* ph = rhhi + (size_t)b0 * H_;
      const u16* pl = rhlo + (size_t)b0 * H_;
#pragma unroll
      for (int k = 0; k < 128; k += 32) {
        short8 hi = frag_coh(ph, H_, w * 128 + k);
        short8 lo = frag_coh(pl, H_, w * 128 + k);
        ah = acc3(ah, hi, lo, wh_hi, wh_lo, KPADB, w * 128 + k);
      }
    }

    *reinterpret_cast<floatx4*>(&sRedF[((0 * 4 + w) * 16 + (l & 15)) * 16 + ((l >> 4) << 2)]) = ah;
    __syncthreads();

    const int j = tid >> 4, brow = tid & 15, b = b0 + brow;
    float v = sBias[j];
#pragma unroll
    for (int ww = 0; ww < 4; ++ww) v += sRedF[((0 * 4 + ww) * 16 + j) * 16 + brow];
    float htl = tanhf(v);
    float z = __builtin_bit_cast(float, ald(reinterpret_cast<const u32*>(zb + (size_t)b * H_ + j0 + j)));
    float hv;
    if (t == 0) {
      hv = h0p[(size_t)b * H_ + j0 + j];
    } else {
      const int slot = L ? ((t - 1) & 3) : ((t - 1) & 7);
      const u16* hhi_t = (L ? y1hi : y0hi) + (size_t)slot * B_ * H_;
      const u16* hlo_t = (L ? y1lo : y0lo) + (size_t)slot * B_ * H_;
      hv = pair_coh(hhi_t, hlo_t, (size_t)b * H_ + j0 + j);
    }
    float hn = z * hv + (1.f - z) * htl;

    // ring backpressure: don't overwrite y0 slot until L1 consumed it
    if (L == 0 && t >= 8) wait_all(fH_L1 + bg, 32, 2, t - 7, abortf);

    u16 hn_h = f2bf(hn), hn_l = f2bf(hn - bf2f(hn_h));
    int p_h = __shfl_xor((int)hn_h, 16);
    int p_l = __shfl_xor((int)hn_l, 16);
    {
      const int oslot = L ? (t & 3) : (t & 7);
      u16* oHi = (L ? y1hi : y0hi) + (size_t)oslot * B_ * H_;
      u16* oLo = (L ? y1lo : y0lo) + (size_t)oslot * B_ * H_;
      if ((j & 1) == 0) {
        size_t idx = (size_t)b * H_ + j0 + j;
        store_pair_u16(oHi, idx, hn_h, (u16)p_h);
        store_pair_u16(oLo, idx, hn_l, (u16)p_l);
      }
    }
    if (L == 1) a.out[((size_t)b * S_ + t) * H_ + j0 + j] = hn;
    if (t == S_ - 1) a.out[Y1_ELEMS + (size_t)L * B_ * H_ + (size_t)b * H_ + j0 + j] = hn;

    publish_flag(fH_self + colb * 2 + bg, t + 1);
  }
}

__global__ __launch_bounds__(256, 1) void gru_persist(GruArgs a) {
  // LDS: max role = L1-A: 2 gates * 2 planes * 16 * (1024+8) u16 = 132096 B
  __shared__ u16 sWT[66048];
  __shared__ float sRed[2 * 4 * 16 * 16];
  __shared__ float sBias[2 * 16];
  const int bid = blockIdx.x;
  const int L = bid >> 7;
  const int role = (bid >> 6) & 1;
  const int colb = (bid >> 1) & 31;
  const int bg = bid & 1;
  if (L == 0) {
    if (role == 0) role_A<0>(a, colb, bg, sWT, sRed, sBias);
    else           role_B<0>(a, colb, bg, sWT, sRed, sBias);
  } else {
    if (role == 0) role_A<1>(a, colb, bg, sWT, sRed, sBias);
    else           role_B<1>(a, colb, bg, sWT, sRed, sBias);
  }
}

}  // namespace

extern "C" void kernel_launch(void* const* d_in, const int* in_sizes, int n_in,
                              void* d_out, int out_size, void* d_ws, size_t ws_size,
                              hipStream_t stream) {
  if (ws_size < WS_NEED) return;  // out stays poisoned -> visibly wrong, no crash
  GruArgs a;
  a.x   = (const float*)d_in[0];
  a.h0  = (const float*)d_in[1];
  a.Wz0 = (const float*)d_in[2];  a.bz0 = (const float*)d_in[3];
  a.Wr0 = (const float*)d_in[4];  a.br0 = (const float*)d_in[5];
  a.Wh0 = (const float*)d_in[6];  a.bh0 = (const float*)d_in[7];
  a.Wz1 = (const float*)d_in[8];  a.bz1 = (const float*)d_in[9];
  a.Wr1 = (const float*)d_in[10]; a.br1 = (const float*)d_in[11];
  a.Wh1 = (const float*)d_in[12]; a.bh1 = (const float*)d_in[13];
  a.out = (float*)d_out;
  a.ws  = (char*)d_ws;
  hipLaunchKernelGGL(gru_persist, dim3(256), dim3(256), 0, stream, a);
}

// Round 4
// 34685.233 us; speedup vs baseline: 2.6986x; 2.6986x over previous
//
#include <hip/hip_runtime.h>

#define DEV __device__ __forceinline__

typedef __attribute__((ext_vector_type(8))) short short8;
typedef __attribute__((ext_vector_type(4))) float floatx4;
typedef __attribute__((ext_vector_type(2))) unsigned long long u64x2;
typedef unsigned short u16;
typedef unsigned int u32;
typedef unsigned long long u64;

namespace {

constexpr int B_ = 32;
constexpr int S_ = 2048;
constexpr int IN0 = 256;
constexpr int H_ = 512;
constexpr size_t Y1_ELEMS = (size_t)B_ * S_ * H_;
constexpr u32 BASE_U = 0xAAAAAAAAu;  // ws poison pattern as u32

// ---- workspace layout (bytes). ws is poisoned 0xAA each launch; counters
// start at BASE_U and only ever increment (thresholds are value-BASE_U).
constexpr size_t O_Y0HI = 0;                                  // u16 [8][32][512] ring
constexpr size_t O_Y0LO = O_Y0HI + (size_t)8 * B_ * H_ * 2;
constexpr size_t O_Y1HI = O_Y0LO + (size_t)8 * B_ * H_ * 2;   // u16 [4][32][512] ring
constexpr size_t O_Y1LO = O_Y1HI + (size_t)4 * B_ * H_ * 2;
constexpr size_t O_RHHI = O_Y1LO + (size_t)4 * B_ * H_ * 2;   // u16 [2][32][512]
constexpr size_t O_RHLO = O_RHHI + (size_t)2 * B_ * H_ * 2;
constexpr size_t O_ZBUF = O_RHLO + (size_t)2 * B_ * H_ * 2;   // f32 [2][32][512]
constexpr size_t O_FLAG = O_ZBUF + (size_t)2 * B_ * H_ * 4;   // counters, 128B apart
constexpr size_t WS_NEED = O_FLAG + 4096;
// counter slots (idx*128 bytes): 0..3 cA[L][bg], 4..7 cH[L][bg], 8 abort

struct GruArgs {
  const float* x;  const float* h0;
  const float* Wz0; const float* bz0; const float* Wr0; const float* br0;
  const float* Wh0; const float* bh0;
  const float* Wz1; const float* bz1; const float* Wr1; const float* br1;
  const float* Wh1; const float* bh1;
  float* out; char* ws;
};

DEV u16 f2bf(float f) {  // RNE fp32 -> bf16 bits
  u32 u = __builtin_bit_cast(u32, f);
  return (u16)((u + 0x7fffu + ((u >> 16) & 1u)) >> 16);
}
DEV float bf2f(u16 h) { u32 u = ((u32)h) << 16; return __builtin_bit_cast(float, u); }

DEV int* cslot(char* ws, int idx) { return (int*)(ws + O_FLAG + (size_t)idx * 128); }

// Agent-scope coherent loads (sc0+sc1: bypass L1/L2, read coherence point).
DEV u32 ald32(const u32* p) {
  return __hip_atomic_load(p, __ATOMIC_RELAXED, __HIP_MEMORY_SCOPE_AGENT);
}
DEV u64 ald64(const u64* p) {
  return __hip_atomic_load(p, __ATOMIC_RELAXED, __HIP_MEMORY_SCOPE_AGENT);
}

// A/B fragment for mfma_f32_16x16x32_bf16:
//   A: row = lane&15, k = 8*(lane>>4)+e ; B: col = lane&15, k = 8*(lane>>4)+e
//   D: col = lane&15, row = 4*(lane>>4)+reg
DEV short8 frag_lds(const u16* base, int ld, int k0) {  // LDS weights (plain)
  const int l = threadIdx.x & 63;
  return *reinterpret_cast<const short8*>(base + (size_t)(l & 15) * ld + k0 + ((l >> 4) << 3));
}
DEV short8 frag_coh(const u16* base, int ld, int k0) {  // cross-block ring planes
  const int l = threadIdx.x & 63;
  const u64* p = reinterpret_cast<const u64*>(base + (size_t)(l & 15) * ld + k0 + ((l >> 4) << 3));
  u64x2 w;
  w[0] = ald64(p + 0);
  w[1] = ald64(p + 1);
  return __builtin_bit_cast(short8, w);
}
// Coherent scalar read of hi/lo bf16 plane pair -> fp32
DEV float pair_coh(const u16* hi, const u16* lo, size_t idx) {
  const size_t e = idx & ~(size_t)1;
  u32 wh = ald32(reinterpret_cast<const u32*>(hi + e));
  u32 wl = ald32(reinterpret_cast<const u32*>(lo + e));
  const int sh = (int)(idx & 1) * 16;
  return bf2f((u16)(wh >> sh)) + bf2f((u16)(wl >> sh));
}
DEV void frag_f32(const float* base, size_t ld, int k0, short8& hi, short8& lo) {
  const int l = threadIdx.x & 63;
  const float* p = base + (size_t)(l & 15) * ld + k0 + ((l >> 4) << 3);
  float4 a = *reinterpret_cast<const float4*>(p);
  float4 b = *reinterpret_cast<const float4*>(p + 4);
  float v[8] = {a.x, a.y, a.z, a.w, b.x, b.y, b.z, b.w};
#pragma unroll
  for (int e = 0; e < 8; ++e) {
    u16 h = f2bf(v[e]);
    hi[e] = (short)h;
    lo[e] = (short)f2bf(v[e] - bf2f(h));
  }
}

// 3-term hi/lo split product accumulate (drops lo*lo, ~2^-17 rel)
DEV floatx4 acc3(floatx4 c, short8 ahi, short8 alo, const u16* whi, const u16* wlo,
                 int ld, int k0) {
  short8 bh = frag_lds(whi, ld, k0);
  short8 bl = frag_lds(wlo, ld, k0);
  c = __builtin_amdgcn_mfma_f32_16x16x32_bf16(ahi, bh, c, 0, 0, 0);
  c = __builtin_amdgcn_mfma_f32_16x16x32_bf16(alo, bh, c, 0, 0, 0);
  c = __builtin_amdgcn_mfma_f32_16x16x32_bf16(ahi, bl, c, 0, 0, 0);
  return c;
}

// Wait until (c0-BASE) >= tgt0 [lane 0] and, if c1 != nullptr, (c1-BASE) >=
// tgt1 [lane 1]. One poll load in flight per block per counter. No HW acquire
// fence: all cross-block data is read via sc-bypassing atomic loads, which
// cannot hit stale L1/L2; signal_fence stops compiler reordering only.
DEV void waitc(int* c0, u32 tgt0, int* c1, u32 tgt1, int* abortf) {
  const int tid = threadIdx.x;
  if (tid < 2) {
    int* p = (tid == 0) ? c0 : c1;
    u32 tgt = (tid == 0) ? tgt0 : tgt1;
    if (p != nullptr) {
      int it = 0;
      while ((u32)((u32)__hip_atomic_load(p, __ATOMIC_RELAXED, __HIP_MEMORY_SCOPE_AGENT) - BASE_U) < tgt) {
        __builtin_amdgcn_s_sleep(1);
        if ((++it & 1023) == 0) {
          if (__hip_atomic_load(abortf, __ATOMIC_RELAXED, __HIP_MEMORY_SCOPE_AGENT) == 1234567) break;
          if (it > (1 << 22)) {
            __hip_atomic_store(abortf, 1234567, __ATOMIC_RELAXED, __HIP_MEMORY_SCOPE_AGENT);
            break;
          }
        }
      }
    }
  }
  __atomic_signal_fence(__ATOMIC_ACQUIRE);
  __syncthreads();
}

// Publish: barrier drains every thread's outstanding (write-through) stores
// (compiler emits s_waitcnt vmcnt(0) before s_barrier), then one release-RMW
// increments the aggregate counter. Chained RMWs preserve each producer's
// release sequence, so a consumer acquire-read of the sum sees all data.
DEV void publish(int* c) {
  __atomic_signal_fence(__ATOMIC_RELEASE);
  __syncthreads();
  if (threadIdx.x == 0)
    (void)__hip_atomic_fetch_add(c, 1, __ATOMIC_RELEASE, __HIP_MEMORY_SCOPE_AGENT);
}

DEV void store_pair_u16(u16* plane, size_t idx_even, u16 el_lo, u16 el_hi) {
  u32 v = (u32)el_lo | ((u32)el_hi << 16);
  __hip_atomic_store(reinterpret_cast<u32*>(plane + idx_even), v,
                     __ATOMIC_RELAXED, __HIP_MEMORY_SCOPE_AGENT);
}

// ---------------- Role A: z,r gates + publish r*h (hi/lo planes) + z --------
template <int L>
DEV void role_A(const GruArgs& a, int colb, int bg, u16* sWT, float* sRedF, float* sBias) {
  constexpr int KX = (L == 0) ? IN0 : H_;   // input-part K
  constexpr int KPAD = KX + H_ + 8;         // LDS row stride (u16), keeps 16B align
  constexpr int KXq = KX / 4;               // per-wave input-part slice
  const int tid = threadIdx.x;
  const int w = tid >> 6;
  const int l = tid & 63;
  const int j0 = colb * 16, b0 = bg * 16;

  const float* Wz = L ? a.Wz1 : a.Wz0;
  const float* Wr = L ? a.Wr1 : a.Wr0;
  const float* bz = L ? a.bz1 : a.bz0;
  const float* br = L ? a.br1 : a.br0;

  // pack weight slice hi/lo into LDS, layout [gate][plane][16 cols][KPAD]
  for (int g = 0; g < 2; ++g) {
    const float* W = g ? Wr : Wz;
    const int c = tid & 15;
    for (int k = tid >> 4; k < KX + H_; k += 16) {
      float v = W[(size_t)k * H_ + j0 + c];
      u16 h = f2bf(v), lo = f2bf(v - bf2f(h));
      sWT[((size_t)(g * 2 + 0) * 16 + c) * KPAD + k] = h;
      sWT[((size_t)(g * 2 + 1) * 16 + c) * KPAD + k] = lo;
    }
  }
  if (tid < 16) { sBias[0 * 16 + tid] = bz[j0 + tid]; sBias[1 * 16 + tid] = br[j0 + tid]; }
  __syncthreads();

  char* ws = a.ws;
  u16* y0hi = (u16*)(ws + O_Y0HI); u16* y0lo = (u16*)(ws + O_Y0LO);
  u16* y1hi = (u16*)(ws + O_Y1HI); u16* y1lo = (u16*)(ws + O_Y1LO);
  u16* rhhi = (u16*)(ws + O_RHHI) + (size_t)L * B_ * H_;
  u16* rhlo = (u16*)(ws + O_RHLO) + (size_t)L * B_ * H_;
  float* zb = (float*)(ws + O_ZBUF) + (size_t)L * B_ * H_;
  int* cA_mine = cslot(ws, L * 2 + bg);
  int* cH_L0   = cslot(ws, 4 + 0 * 2 + bg);
  int* cH_self = cslot(ws, 4 + L * 2 + bg);
  int* abortf  = cslot(ws, 8);
  const float* h0p = a.h0 + (size_t)L * B_ * H_;

  const u16* wz_hi = sWT + (size_t)0 * 16 * KPAD;
  const u16* wz_lo = sWT + (size_t)1 * 16 * KPAD;
  const u16* wr_hi = sWT + (size_t)2 * 16 * KPAD;
  const u16* wr_lo = sWT + (size_t)3 * 16 * KPAD;

  for (int t = 0; t < S_; ++t) {
    floatx4 az = {0.f, 0.f, 0.f, 0.f};
    floatx4 ar = {0.f, 0.f, 0.f, 0.f};

    // ---- input-part of z,r  (x for L0: no wait; y0(t) for L1)
    if constexpr (L == 0) {
      const float* xb = a.x + ((size_t)b0 * S_ + t) * IN0;
#pragma unroll
      for (int k = 0; k < KXq; k += 32) {
        short8 hi, lo;
        frag_f32(xb, (size_t)S_ * IN0, w * KXq + k, hi, lo);
        az = acc3(az, hi, lo, wz_hi, wz_lo, KPAD, w * KXq + k);
        ar = acc3(ar, hi, lo, wr_hi, wr_lo, KPAD, w * KXq + k);
      }
      if (t > 0) waitc(cH_self, 32u * (u32)t, nullptr, 0, abortf);
    } else {
      // y0(t) ready AND (t>0) h(t-1) ready — one combined wait
      waitc(cH_L0, 32u * (u32)(t + 1), (t > 0) ? cH_self : nullptr, 32u * (u32)t, abortf);
      const u16* ph = y0hi + ((size_t)(t & 7) * B_ + b0) * H_;
      const u16* pl = y0lo + ((size_t)(t & 7) * B_ + b0) * H_;
#pragma unroll
      for (int k = 0; k < KXq; k += 32) {
        short8 hi = frag_coh(ph, H_, w * KXq + k);
        short8 lo = frag_coh(pl, H_, w * KXq + k);
        az = acc3(az, hi, lo, wz_hi, wz_lo, KPAD, w * KXq + k);
        ar = acc3(ar, hi, lo, wr_hi, wr_lo, KPAD, w * KXq + k);
      }
    }

    // ---- hidden-part of z,r
    const u16* hhi_t = nullptr; const u16* hlo_t = nullptr;  // row-0 base of h(t) planes
    if (t > 0) {
      const int slot = L ? ((t - 1) & 3) : ((t - 1) & 7);
      hhi_t = (L ? y1hi : y0hi) + (size_t)slot * B_ * H_;
      hlo_t = (L ? y1lo : y0lo) + (size_t)slot * B_ * H_;
      const u16* ph = hhi_t + (size_t)b0 * H_;
      const u16* pl = hlo_t + (size_t)b0 * H_;
#pragma unroll
      for (int k = 0; k < 128; k += 32) {
        short8 hi = frag_coh(ph, H_, w * 128 + k);
        short8 lo = frag_coh(pl, H_, w * 128 + k);
        az = acc3(az, hi, lo, wz_hi, wz_lo, KPAD, KX + w * 128 + k);
        ar = acc3(ar, hi, lo, wr_hi, wr_lo, KPAD, KX + w * 128 + k);
      }
    } else {
      const float* hb = h0p + (size_t)b0 * H_;
#pragma unroll
      for (int k = 0; k < 128; k += 32) {
        short8 hi, lo;
        frag_f32(hb, (size_t)H_, w * 128 + k, hi, lo);
        az = acc3(az, hi, lo, wz_hi, wz_lo, KPAD, KX + w * 128 + k);
        ar = acc3(ar, hi, lo, wr_hi, wr_lo, KPAD, KX + w * 128 + k);
      }
    }

    // ---- cross-wave K reduce: sRed[gate][wave][col][row]
    *reinterpret_cast<floatx4*>(&sRedF[((0 * 4 + w) * 16 + (l & 15)) * 16 + ((l >> 4) << 2)]) = az;
    *reinterpret_cast<floatx4*>(&sRedF[((1 * 4 + w) * 16 + (l & 15)) * 16 + ((l >> 4) << 2)]) = ar;
    __syncthreads();
    {
      const int j = tid >> 4, brow = tid & 15, b = b0 + brow;
      float vz = sBias[0 * 16 + j], vr = sBias[1 * 16 + j];
#pragma unroll
      for (int ww = 0; ww < 4; ++ww) {
        vz += sRedF[((0 * 4 + ww) * 16 + j) * 16 + brow];
        vr += sRedF[((1 * 4 + ww) * 16 + j) * 16 + brow];
      }
      float z = 1.f / (1.f + expf(-vz));
      float r = 1.f / (1.f + expf(-vr));
      float hv = (t == 0) ? h0p[(size_t)b * H_ + j0 + j]
                          : pair_coh(hhi_t, hlo_t, (size_t)b * H_ + j0 + j);
      float rh = r * hv;
      u16 rh_h = f2bf(rh), rh_l = f2bf(rh - bf2f(rh_h));
      int prt_h = __shfl_xor((int)rh_h, 16);
      int prt_l = __shfl_xor((int)rh_l, 16);
      if ((j & 1) == 0) {
        size_t idx = (size_t)b * H_ + j0 + j;
        store_pair_u16(rhhi, idx, rh_h, (u16)prt_h);
        store_pair_u16(rhlo, idx, rh_l, (u16)prt_l);
      }
      __hip_atomic_store(zb + (size_t)b * H_ + j0 + j, z, __ATOMIC_RELAXED, __HIP_MEMORY_SCOPE_AGENT);
    }
    publish(cA_mine);
  }
}

// ---------------- Role B: h_tilde + state update + publish h planes --------
template <int L>
DEV void role_B(const GruArgs& a, int colb, int bg, u16* sWT, float* sRedF, float* sBias) {
  constexpr int KX = (L == 0) ? IN0 : H_;
  constexpr int KPADB = H_ + 8;  // 520, shared stride for both gates
  constexpr int KXq = KX / 4;
  const int tid = threadIdx.x;
  const int w = tid >> 6;
  const int l = tid & 63;
  const int j0 = colb * 16, b0 = bg * 16;

  const float* Wh = L ? a.Wh1 : a.Wh0;
  const float* bh = L ? a.bh1 : a.bh0;

  // gate0 = x-part rows [0,KX), gate1 = h-part rows [KX,KX+512)
  {
    const int c = tid & 15;
    for (int k = tid >> 4; k < KX; k += 16) {
      float v = Wh[(size_t)k * H_ + j0 + c];
      u16 h = f2bf(v), lo = f2bf(v - bf2f(h));
      sWT[((size_t)0 * 16 + c) * KPADB + k] = h;
      sWT[((size_t)1 * 16 + c) * KPADB + k] = lo;
    }
    for (int k = tid >> 4; k < H_; k += 16) {
      float v = Wh[(size_t)(KX + k) * H_ + j0 + c];
      u16 h = f2bf(v), lo = f2bf(v - bf2f(h));
      sWT[((size_t)2 * 16 + c) * KPADB + k] = h;
      sWT[((size_t)3 * 16 + c) * KPADB + k] = lo;
    }
  }
  if (tid < 16) sBias[tid] = bh[j0 + tid];
  __syncthreads();

  char* ws = a.ws;
  u16* y0hi = (u16*)(ws + O_Y0HI); u16* y0lo = (u16*)(ws + O_Y0LO);
  u16* y1hi = (u16*)(ws + O_Y1HI); u16* y1lo = (u16*)(ws + O_Y1LO);
  u16* rhhi = (u16*)(ws + O_RHHI) + (size_t)L * B_ * H_;
  u16* rhlo = (u16*)(ws + O_RHLO) + (size_t)L * B_ * H_;
  float* zb = (float*)(ws + O_ZBUF) + (size_t)L * B_ * H_;
  int* cA_src  = cslot(ws, L * 2 + bg);
  int* cH_mine = cslot(ws, 4 + L * 2 + bg);
  int* cH_L0   = cslot(ws, 4 + 0 * 2 + bg);
  int* cH_L1   = cslot(ws, 4 + 1 * 2 + bg);
  int* abortf  = cslot(ws, 8);
  const float* h0p = a.h0 + (size_t)L * B_ * H_;

  const u16* wx_hi = sWT + (size_t)0 * 16 * KPADB;
  const u16* wx_lo = sWT + (size_t)1 * 16 * KPADB;
  const u16* wh_hi = sWT + (size_t)2 * 16 * KPADB;
  const u16* wh_lo = sWT + (size_t)3 * 16 * KPADB;

  for (int t = 0; t < S_; ++t) {
    floatx4 ah = {0.f, 0.f, 0.f, 0.f};

    // ---- x-part of h_tilde preact
    if constexpr (L == 0) {
      const float* xb = a.x + ((size_t)b0 * S_ + t) * IN0;
#pragma unroll
      for (int k = 0; k < KXq; k += 32) {
        short8 hi, lo;
        frag_f32(xb, (size_t)S_ * IN0, w * KXq + k, hi, lo);
        ah = acc3(ah, hi, lo, wx_hi, wx_lo, KPADB, w * KXq + k);
      }
      // rh ready AND (t>=8) y0 ring slot free — one combined wait
      waitc(cA_src, 32u * (u32)(t + 1),
            (t >= 8) ? cH_L1 : nullptr, 32u * (u32)(t - 7), abortf);
    } else {
      waitc(cH_L0, 32u * (u32)(t + 1), nullptr, 0, abortf);
      const u16* ph = y0hi + ((size_t)(t & 7) * B_ + b0) * H_;
      const u16* pl = y0lo + ((size_t)(t & 7) * B_ + b0) * H_;
#pragma unroll
      for (int k = 0; k < KXq; k += 32) {
        short8 hi = frag_coh(ph, H_, w * KXq + k);
        short8 lo = frag_coh(pl, H_, w * KXq + k);
        ah = acc3(ah, hi, lo, wx_hi, wx_lo, KPADB, w * KXq + k);
      }
      waitc(cA_src, 32u * (u32)(t + 1), nullptr, 0, abortf);
    }

    // ---- (r*h) @ Whh : rh from ALL 32 colb producers of this (L,bg)
    {
      const u16* ph = rhhi + (size_t)b0 * H_;
      const u16* pl = rhlo + (size_t)b0 * H_;
#pragma unroll
      for (int k = 0; k < 128; k += 32) {
        short8 hi = frag_coh(ph, H_, w * 128 + k);
        short8 lo = frag_coh(pl, H_, w * 128 + k);
        ah = acc3(ah, hi, lo, wh_hi, wh_lo, KPADB, w * 128 + k);
      }
    }

    *reinterpret_cast<floatx4*>(&sRedF[((0 * 4 + w) * 16 + (l & 15)) * 16 + ((l >> 4) << 2)]) = ah;
    __syncthreads();

    const int j = tid >> 4, brow = tid & 15, b = b0 + brow;
    float v = sBias[j];
#pragma unroll
    for (int ww = 0; ww < 4; ++ww) v += sRedF[((0 * 4 + ww) * 16 + j) * 16 + brow];
    float htl = tanhf(v);
    float z = __builtin_bit_cast(float, ald32(reinterpret_cast<const u32*>(zb + (size_t)b * H_ + j0 + j)));
    float hv;
    if (t == 0) {
      hv = h0p[(size_t)b * H_ + j0 + j];
    } else {
      const int slot = L ? ((t - 1) & 3) : ((t - 1) & 7);
      const u16* hhi_t = (L ? y1hi : y0hi) + (size_t)slot * B_ * H_;
      const u16* hlo_t = (L ? y1lo : y0lo) + (size_t)slot * B_ * H_;
      hv = pair_coh(hhi_t, hlo_t, (size_t)b * H_ + j0 + j);
    }
    float hn = z * hv + (1.f - z) * htl;

    u16 hn_h = f2bf(hn), hn_l = f2bf(hn - bf2f(hn_h));
    int p_h = __shfl_xor((int)hn_h, 16);
    int p_l = __shfl_xor((int)hn_l, 16);
    {
      const int oslot = L ? (t & 3) : (t & 7);
      u16* oHi = (L ? y1hi : y0hi) + (size_t)oslot * B_ * H_;
      u16* oLo = (L ? y1lo : y0lo) + (size_t)oslot * B_ * H_;
      if ((j & 1) == 0) {
        size_t idx = (size_t)b * H_ + j0 + j;
        store_pair_u16(oHi, idx, hn_h, (u16)p_h);
        store_pair_u16(oLo, idx, hn_l, (u16)p_l);
      }
    }
    if (L == 1) a.out[((size_t)b * S_ + t) * H_ + j0 + j] = hn;
    if (t == S_ - 1) a.out[Y1_ELEMS + (size_t)L * B_ * H_ + (size_t)b * H_ + j0 + j] = hn;

    publish(cH_mine);
  }
}

__global__ __launch_bounds__(256, 1) void gru_persist(GruArgs a) {
  // LDS: max role = L1-A: 2 gates * 2 planes * 16 * (1024+8) u16 = 132096 B
  __shared__ u16 sWT[66048];
  __shared__ float sRed[2 * 4 * 16 * 16];
  __shared__ float sBias[2 * 16];
  const int bid = blockIdx.x;
  const int L = bid >> 7;
  const int role = (bid >> 6) & 1;
  const int colb = (bid >> 1) & 31;
  const int bg = bid & 1;
  if (L == 0) {
    if (role == 0) role_A<0>(a, colb, bg, sWT, sRed, sBias);
    else           role_B<0>(a, colb, bg, sWT, sRed, sBias);
  } else {
    if (role == 0) role_A<1>(a, colb, bg, sWT, sRed, sBias);
    else           role_B<1>(a, colb, bg, sWT, sRed, sBias);
  }
}

}  // namespace

extern "C" void kernel_launch(void* const* d_in, const int* in_sizes, int n_in,
                              void* d_out, int out_size, void* d_ws, size_t ws_size,
                              hipStream_t stream) {
  if (ws_size < WS_NEED) return;  // out stays poisoned -> visibly wrong, no crash
  GruArgs a;
  a.x   = (const float*)d_in[0];
  a.h0  = (const float*)d_in[1];
  a.Wz0 = (const float*)d_in[2];  a.bz0 = (const float*)d_in[3];
  a.Wr0 = (const float*)d_in[4];  a.br0 = (const float*)d_in[5];
  a.Wh0 = (const float*)d_in[6];  a.bh0 = (const float*)d_in[7];
  a.Wz1 = (const float*)d_in[8];  a.bz1 = (const float*)d_in[9];
  a.Wr1 = (const float*)d_in[10]; a.br1 = (const float*)d_in[11];
  a.Wh1 = (const float*)d_in[12]; a.bh1 = (const float*)d_in[13];
  a.out = (float*)d_out;
  a.ws  = (char*)d_ws;
  hipLaunchKernelGGL(gru_persist, dim3(256), dim3(256), 0, stream, a);
}